// Round 4
// baseline (1185.318 us; speedup 1.0000x reference)
//
#include <hip/hip_runtime.h>
#include <hip/hip_bf16.h>

#define LSPANS 4096
#define BB 32
#define HH 1024
#define DD 1024
#define VV 32000
#define K1 2048   // 2H
#define NT2 250   // V / 128

typedef unsigned short u16;
typedef unsigned char u8;
typedef __attribute__((ext_vector_type(8))) short bf16x8v;
typedef __attribute__((ext_vector_type(4))) float f32x4v;
typedef __attribute__((ext_vector_type(8))) int i32x8v;
typedef __attribute__((ext_vector_type(4))) int i32x4v;

#define SCALE1 0x7F7F7F7F   // e8m0 = 127 -> 2^0 in every byte

__device__ __forceinline__ u16 f2bf(float x) {
  union { float f; unsigned u; } v; v.f = x;
  unsigned r = (v.u >> 16) & 1u;
  return (u16)((v.u + 0x7fffu + r) >> 16);
}

__device__ __forceinline__ int pk4_fp8(float a, float b, float c, float d) {
  int p = __builtin_amdgcn_cvt_pk_fp8_f32(a, b, 0, false);
  p = __builtin_amdgcn_cvt_pk_fp8_f32(c, d, p, true);
  return p;
}

// ---------------- fp32 -> bf16 bulk convert (vector x4) ----------------
__global__ void cvt_kernel(const float* __restrict__ in, u16* __restrict__ out, int n4) {
  int i = blockIdx.x * blockDim.x + threadIdx.x;
  int stride = gridDim.x * blockDim.x;
  for (; i < n4; i += stride) {
    float4 v = ((const float4*)in)[i];
    ushort4 o;
    o.x = f2bf(v.x); o.y = f2bf(v.y); o.z = f2bf(v.z); o.w = f2bf(v.w);
    ((ushort4*)out)[i] = o;
  }
}

// ---------------- fp32 -> fp8 e4m3 bulk convert ----------------
__global__ void cvt_fp8_kernel(const float* __restrict__ in, int* __restrict__ out, int n4) {
  int i = blockIdx.x * blockDim.x + threadIdx.x;
  int stride = gridDim.x * blockDim.x;
  for (; i < n4; i += stride) {
    float4 v = ((const float4*)in)[i];
    out[i] = pk4_fp8(v.x, v.y, v.z, v.w);
  }
}

// ---------------- gather span endpoints -> bf16 [L, 2H] ----------------
__global__ void gather_kernel(const float* __restrict__ hidden,
                              const int* __restrict__ bid,
                              const int* __restrict__ sb,
                              const int* __restrict__ se,
                              u16* __restrict__ out) {
  int l = blockIdx.x;
  int t = threadIdx.x;
  int b  = bid[l];
  const float* p0 = hidden + ((size_t)sb[l] * BB + b) * HH;
  const float* p1 = hidden + ((size_t)se[l] * BB + b) * HH;
  u16* dst = out + (size_t)l * K1;
  float4 v0 = ((const float4*)p0)[t];
  float4 v1 = ((const float4*)p1)[t];
  ushort4 o0; o0.x = f2bf(v0.x); o0.y = f2bf(v0.y); o0.z = f2bf(v0.z); o0.w = f2bf(v0.w);
  ushort4 o1; o1.x = f2bf(v1.x); o1.y = f2bf(v1.y); o1.z = f2bf(v1.z); o1.w = f2bf(v1.w);
  ((ushort4*)dst)[t]          = o0;
  ((ushort4*)(dst + HH))[t]   = o1;
}

// ---------------- GEMM1: 128x128 bf16 MFMA, tanh+bias epilogue -> fp8 feat ----
// XOR-swizzled LDS: LDS[r][c16] = G[r][c16 ^ (r&7)], chunk = 16 B.
__launch_bounds__(256, 2)
__global__ void gemm1_kernel(const u16* __restrict__ A, const u16* __restrict__ B,
                             const float* __restrict__ bias, u8* __restrict__ feat_out) {
  __shared__ __align__(16) u16 As[128 * 64];
  __shared__ __align__(16) u16 Bs[128 * 64];

  const int tid  = threadIdx.x;
  const int lane = tid & 63;
  const int w    = tid >> 6;
  const int wm   = w & 1;
  const int wn   = w >> 1;
  const int q    = lane >> 4;
  const int lm   = lane & 15;
  const int mBase = blockIdx.x * 128;
  const int nBase = blockIdx.y * 128;

  f32x4v acc[4][4];
#pragma unroll
  for (int i = 0; i < 4; ++i)
#pragma unroll
    for (int j = 0; j < 4; ++j) acc[i][j] = (f32x4v){0.f, 0.f, 0.f, 0.f};

  const int srow = w * 32 + (lane >> 3);
  const int scol = ((lane & 7) ^ (lane >> 3)) * 8;
  const u16* Ag = A + (size_t)(mBase + srow) * K1 + scol;
  const u16* Bg = B + (size_t)(nBase + srow) * K1 + scol;

  for (int k0 = 0; k0 < K1; k0 += 64) {
#pragma unroll
    for (int c = 0; c < 4; ++c) {
      __builtin_amdgcn_global_load_lds(
          (const __attribute__((address_space(1))) void*)(Ag + k0 + (size_t)c * 8 * K1),
          (__attribute__((address_space(3))) void*)(As + (w * 32 + c * 8) * 64), 16, 0, 0);
    }
#pragma unroll
    for (int c = 0; c < 4; ++c) {
      __builtin_amdgcn_global_load_lds(
          (const __attribute__((address_space(1))) void*)(Bg + k0 + (size_t)c * 8 * K1),
          (__attribute__((address_space(3))) void*)(Bs + (w * 32 + c * 8) * 64), 16, 0, 0);
    }
    __syncthreads();
#pragma unroll
    for (int kk = 0; kk < 64; kk += 32) {
      bf16x8v af[4], bfr[4];
      const int sw = lm & 7;
#pragma unroll
      for (int i = 0; i < 4; ++i) {
        int row = wm * 64 + i * 16 + lm;
        int kch = (kk >> 3) + q;
        af[i] = *(const bf16x8v*)(As + row * 64 + ((kch ^ sw) << 3));
      }
#pragma unroll
      for (int j = 0; j < 4; ++j) {
        int row = wn * 64 + j * 16 + lm;
        int kch = (kk >> 3) + q;
        bfr[j] = *(const bf16x8v*)(Bs + row * 64 + ((kch ^ sw) << 3));
      }
#pragma unroll
      for (int i = 0; i < 4; ++i)
#pragma unroll
        for (int j = 0; j < 4; ++j)
          acc[i][j] = __builtin_amdgcn_mfma_f32_16x16x32_bf16(af[i], bfr[j], acc[i][j], 0, 0, 0);
    }
    __syncthreads();
  }

  // C/D layout: col = lane&15, row = quad*4 + reg
  float bj[4];
#pragma unroll
  for (int j = 0; j < 4; ++j) bj[j] = bias[nBase + wn * 64 + j * 16 + lm];
#pragma unroll
  for (int i = 0; i < 4; ++i)
#pragma unroll
    for (int j = 0; j < 4; ++j)
#pragma unroll
      for (int r = 0; r < 4; ++r) {
        int tr = wm * 64 + i * 16 + q * 4 + r;
        int tc = wn * 64 + j * 16 + lm;
        float v = tanhf(acc[i][j][r] + bj[j]);
        int p = __builtin_amdgcn_cvt_pk_fp8_f32(v, v, 0, false);
        feat_out[(size_t)(mBase + tr) * DD + nBase + tc] = (u8)(p & 0xff);
      }
}

// ---------------- GEMM2: 128x128 MX-fp8 MFMA (K=128/inst), softmax partials ----
// Register-pressure discipline (round-3 spill fix):
//  - operand concat via __builtin_shufflevector (no stack temp / SROA failure)
//  - af[4] resident (32 VGPRs); bfr streamed one fragment at a time (8 VGPRs)
//  live ≈ 64 acc + 32 af + 8 bfr + addr ≈ 120 regs.
__launch_bounds__(256, 2)
__global__ void gemm2_kernel(const u8* __restrict__ A, const u8* __restrict__ B,
                             const int* __restrict__ tags,
                             float* __restrict__ pmax, float* __restrict__ psum,
                             float* __restrict__ ltag) {
  __shared__ __align__(16) u8 As[128 * 128];
  __shared__ __align__(16) u8 Bs[128 * 128];
  __shared__ float rmax[2][128];
  __shared__ float rsum[2][128];
  __shared__ int   stags[128];

  const int tid  = threadIdx.x;
  const int lane = tid & 63;
  const int w    = tid >> 6;
  const int wm   = w & 1;
  const int wn   = w >> 1;
  const int q    = lane >> 4;
  const int lm   = lane & 15;
  const int mBase = blockIdx.x * 128;
  const int nBase = blockIdx.y * 128;

  if (tid < 128) stags[tid] = tags[mBase + tid];

  f32x4v acc[4][4];
#pragma unroll
  for (int i = 0; i < 4; ++i)
#pragma unroll
    for (int j = 0; j < 4; ++j) acc[i][j] = (f32x4v){0.f, 0.f, 0.f, 0.f};

  // staging: lane i -> LDS row (i>>3), chunk (i&7); fetches global chunk
  // (i&7)^(i>>3) so LDS[r][c] = G[r][c ^ (r&7)]  (chunks are 16 B).
  const int srow = w * 32 + (lane >> 3);
  const int scol = ((lane & 7) ^ (lane >> 3)) * 16;   // bytes
  const u8* Ag = A + (size_t)(mBase + srow) * DD + scol;
  const u8* Bg = B + (size_t)(nBase + srow) * DD + scol;

  for (int k0 = 0; k0 < DD; k0 += 128) {
#pragma unroll
    for (int c = 0; c < 4; ++c) {
      __builtin_amdgcn_global_load_lds(
          (const __attribute__((address_space(1))) void*)(Ag + k0 + (size_t)c * 8 * DD),
          (__attribute__((address_space(3))) void*)(As + (w * 32 + c * 8) * 128), 16, 0, 0);
    }
#pragma unroll
    for (int c = 0; c < 4; ++c) {
      __builtin_amdgcn_global_load_lds(
          (const __attribute__((address_space(1))) void*)(Bg + k0 + (size_t)c * 8 * DD),
          (__attribute__((address_space(3))) void*)(Bs + (w * 32 + c * 8) * 128), 16, 0, 0);
    }
    __syncthreads();

    // lane (m=lm, kgroup=q) needs global chunks 2q, 2q+1 of its row
    const int sw = lm & 7;
    const int c0 = ((2 * q) ^ sw) * 16;
    const int c1 = ((2 * q + 1) ^ sw) * 16;
    i32x8v af[4];
#pragma unroll
    for (int i = 0; i < 4; ++i) {
      int row = wm * 64 + i * 16 + lm;
      i32x4v lo = *(const i32x4v*)(As + row * 128 + c0);
      i32x4v hi = *(const i32x4v*)(As + row * 128 + c1);
      af[i] = __builtin_shufflevector(lo, hi, 0, 1, 2, 3, 4, 5, 6, 7);
    }
#pragma unroll
    for (int j = 0; j < 4; ++j) {
      int row = wn * 64 + j * 16 + lm;
      i32x4v lo = *(const i32x4v*)(Bs + row * 128 + c0);
      i32x4v hi = *(const i32x4v*)(Bs + row * 128 + c1);
      i32x8v bfr = __builtin_shufflevector(lo, hi, 0, 1, 2, 3, 4, 5, 6, 7);
#pragma unroll
      for (int i = 0; i < 4; ++i)
        acc[i][j] = __builtin_amdgcn_mfma_scale_f32_16x16x128_f8f6f4(
            af[i], bfr, acc[i][j], 0, 0, 0, SCALE1, 0, SCALE1);
    }
    __syncthreads();
  }

  // C/D layout: col = lane&15, row = quad*4 + reg
  // phase 1: per-row max over this wave's 64 cols -> LDS
#pragma unroll
  for (int i = 0; i < 4; ++i)
#pragma unroll
    for (int r = 0; r < 4; ++r) {
      float m = fmaxf(fmaxf(acc[i][0][r], acc[i][1][r]),
                      fmaxf(acc[i][2][r], acc[i][3][r]));
#pragma unroll
      for (int off = 1; off < 16; off <<= 1) m = fmaxf(m, __shfl_xor(m, off, 64));
      if (lm == 0) rmax[wn][wm * 64 + i * 16 + q * 4 + r] = m;
    }
  __syncthreads();
  // phase 2: sumexp against the full 128-col row max
#pragma unroll
  for (int i = 0; i < 4; ++i)
#pragma unroll
    for (int r = 0; r < 4; ++r) {
      int tr = wm * 64 + i * 16 + q * 4 + r;
      float M = fmaxf(rmax[0][tr], rmax[1][tr]);
      float s = __expf(acc[i][0][r] - M) + __expf(acc[i][1][r] - M) +
                __expf(acc[i][2][r] - M) + __expf(acc[i][3][r] - M);
#pragma unroll
      for (int off = 1; off < 16; off <<= 1) s += __shfl_xor(s, off, 64);
      if (lm == 0) rsum[wn][tr] = s;
    }
  __syncthreads();
  if (tid < 128) {
    float M = fmaxf(rmax[0][tid], rmax[1][tid]);
    float S = rsum[0][tid] + rsum[1][tid];
    pmax[(size_t)blockIdx.y * LSPANS + mBase + tid] = M;
    psum[(size_t)blockIdx.y * LSPANS + mBase + tid] = S;
  }
  // tag logit capture (exactly one matching column per row globally)
#pragma unroll
  for (int i = 0; i < 4; ++i)
#pragma unroll
    for (int r = 0; r < 4; ++r) {
      int tr = wm * 64 + i * 16 + q * 4 + r;
      int tg = stags[tr];
#pragma unroll
      for (int j = 0; j < 4; ++j) {
        int gc = nBase + wn * 64 + j * 16 + lm;
        if (tg == gc) ltag[mBase + tr] = acc[i][j][r];
      }
    }
}

// ---------------- merge partials, weighted-mean NLL ----------------
__global__ void finalize_kernel(const float* __restrict__ pmax, const float* __restrict__ psum,
                                const float* __restrict__ ltag, const int* __restrict__ tags,
                                const float* __restrict__ dprob, float* __restrict__ out) {
  int l = blockIdx.x * blockDim.x + threadIdx.x;
  const float* pm = pmax + l;
  const float* ps = psum + l;
  float M = -1e30f;
  for (int t = 0; t < NT2; ++t) M = fmaxf(M, pm[(size_t)t * LSPANS]);
  float S = 0.f;
  for (int t = 0; t < NT2; ++t) S += ps[(size_t)t * LSPANS] * __expf(pm[(size_t)t * LSPANS] - M);
  float nll = M + logf(S) - ltag[l];
  float wgt = 1.0f - dprob[tags[l]];
  float val = nll * wgt * (1.0f / (4096.0f + 1e-5f));
  __shared__ float red[4];
#pragma unroll
  for (int off = 32; off; off >>= 1) val += __shfl_down(val, off, 64);
  if ((threadIdx.x & 63) == 0) red[threadIdx.x >> 6] = val;
  __syncthreads();
  if (threadIdx.x == 0) atomicAdd(out, red[0] + red[1] + red[2] + red[3]);
}

extern "C" void kernel_launch(void* const* d_in, const int* in_sizes, int n_in,
                              void* d_out, int out_size, void* d_ws, size_t ws_size,
                              hipStream_t stream) {
  const float* hidden = (const float*)d_in[0];
  const float* W1     = (const float*)d_in[1];
  const float* b1     = (const float*)d_in[2];
  const float* Wout   = (const float*)d_in[3];
  const float* dprob  = (const float*)d_in[4];
  const int*   bid    = (const int*)d_in[5];
  const int*   sb     = (const int*)d_in[6];
  const int*   se     = (const int*)d_in[7];
  const int*   tags   = (const int*)d_in[8];
  float* out = (float*)d_out;

  char* ws = (char*)d_ws;
  u16* A1     = (u16*)ws;                ws += (size_t)LSPANS * K1 * 2;      // 16.78 MB
  u16* W1b    = (u16*)ws;                ws += (size_t)DD * K1 * 2;          //  4.19 MB
  u8*  Wout8  = (u8*)ws;                 ws += (size_t)VV * DD;              // 32.77 MB
  u8*  feat8  = (u8*)ws;                 ws += (size_t)LSPANS * DD;          //  4.19 MB
  float* pmax = (float*)ws;              ws += (size_t)NT2 * LSPANS * 4;     //  4.10 MB
  float* psum = (float*)ws;              ws += (size_t)NT2 * LSPANS * 4;     //  4.10 MB
  float* ltag = (float*)ws;              ws += (size_t)LSPANS * 4;

  hipMemsetAsync(d_out, 0, sizeof(float), stream);

  // conversions
  {
    int n4 = DD * K1 / 4;
    cvt_kernel<<<(n4 + 255) / 256, 256, 0, stream>>>(W1, W1b, n4);
  }
  {
    int n4 = VV * DD / 4;
    cvt_fp8_kernel<<<(n4 + 255) / 256, 256, 0, stream>>>(Wout, (int*)Wout8, n4);
  }
  // gather span endpoint embeddings
  gather_kernel<<<LSPANS, 256, 0, stream>>>(hidden, bid, sb, se, A1);

  // GEMM1: feat8 = fp8(tanh(A1 @ W1^T + b1))   [4096 x 1024]
  gemm1_kernel<<<dim3(LSPANS / 128, DD / 128), 256, 0, stream>>>(A1, W1b, b1, feat8);

  // GEMM2: MX-fp8 logits tiles + fused softmax partials   [4096 x 32000]
  gemm2_kernel<<<dim3(LSPANS / 128, NT2), 256, 0, stream>>>(feat8, Wout8, tags, pmax, psum, ltag);

  // merge + weighted mean
  finalize_kernel<<<LSPANS / 256, 256, 0, stream>>>(pmax, psum, ltag, tags, dprob, out);
}

// Round 5
// 701.129 us; speedup vs baseline: 1.6906x; 1.6906x over previous
//
#include <hip/hip_runtime.h>
#include <hip/hip_bf16.h>

#define LSPANS 4096
#define BB 32
#define HH 1024
#define DD 1024
#define VV 32000
#define K1 2048   // 2H
#define NT2 250   // V / 128

typedef unsigned short u16;
typedef unsigned char u8;
typedef __attribute__((ext_vector_type(8))) short bf16x8v;
typedef __attribute__((ext_vector_type(4))) float f32x4v;
typedef __attribute__((ext_vector_type(8))) int i32x8v;
typedef __attribute__((ext_vector_type(4))) int i32x4v;

#define SCALE1 0x7F7F7F7F   // e8m0 = 127 -> 2^0 in every byte

__device__ __forceinline__ u16 f2bf(float x) {
  union { float f; unsigned u; } v; v.f = x;
  unsigned r = (v.u >> 16) & 1u;
  return (u16)((v.u + 0x7fffu + r) >> 16);
}

__device__ __forceinline__ int pk4_fp8(float a, float b, float c, float d) {
  int p = __builtin_amdgcn_cvt_pk_fp8_f32(a, b, 0, false);
  p = __builtin_amdgcn_cvt_pk_fp8_f32(c, d, p, true);
  return p;
}

// ---------------- fp32 -> bf16 bulk convert (vector x4) ----------------
__global__ void cvt_kernel(const float* __restrict__ in, u16* __restrict__ out, int n4) {
  int i = blockIdx.x * blockDim.x + threadIdx.x;
  int stride = gridDim.x * blockDim.x;
  for (; i < n4; i += stride) {
    float4 v = ((const float4*)in)[i];
    ushort4 o;
    o.x = f2bf(v.x); o.y = f2bf(v.y); o.z = f2bf(v.z); o.w = f2bf(v.w);
    ((ushort4*)out)[i] = o;
  }
}

// ---------------- fp32 -> fp8 e4m3 bulk convert ----------------
__global__ void cvt_fp8_kernel(const float* __restrict__ in, int* __restrict__ out, int n4) {
  int i = blockIdx.x * blockDim.x + threadIdx.x;
  int stride = gridDim.x * blockDim.x;
  for (; i < n4; i += stride) {
    float4 v = ((const float4*)in)[i];
    out[i] = pk4_fp8(v.x, v.y, v.z, v.w);
  }
}

// ---------------- gather span endpoints -> bf16 [L, 2H] ----------------
__global__ void gather_kernel(const float* __restrict__ hidden,
                              const int* __restrict__ bid,
                              const int* __restrict__ sb,
                              const int* __restrict__ se,
                              u16* __restrict__ out) {
  int l = blockIdx.x;
  int t = threadIdx.x;
  int b  = bid[l];
  const float* p0 = hidden + ((size_t)sb[l] * BB + b) * HH;
  const float* p1 = hidden + ((size_t)se[l] * BB + b) * HH;
  u16* dst = out + (size_t)l * K1;
  float4 v0 = ((const float4*)p0)[t];
  float4 v1 = ((const float4*)p1)[t];
  ushort4 o0; o0.x = f2bf(v0.x); o0.y = f2bf(v0.y); o0.z = f2bf(v0.z); o0.w = f2bf(v0.w);
  ushort4 o1; o1.x = f2bf(v1.x); o1.y = f2bf(v1.y); o1.z = f2bf(v1.z); o1.w = f2bf(v1.w);
  ((ushort4*)dst)[t]          = o0;
  ((ushort4*)(dst + HH))[t]   = o1;
}

// ---------------- GEMM1: 128x128 bf16 MFMA, tanh+bias epilogue -> fp8 feat ----
// XOR-swizzled LDS: LDS[r][c16] = G[r][c16 ^ (r&7)], chunk = 16 B.
__launch_bounds__(256, 2)
__global__ void gemm1_kernel(const u16* __restrict__ A, const u16* __restrict__ B,
                             const float* __restrict__ bias, u8* __restrict__ feat_out) {
  __shared__ __align__(16) u16 As[128 * 64];
  __shared__ __align__(16) u16 Bs[128 * 64];

  const int tid  = threadIdx.x;
  const int lane = tid & 63;
  const int w    = tid >> 6;
  const int wm   = w & 1;
  const int wn   = w >> 1;
  const int q    = lane >> 4;
  const int lm   = lane & 15;
  const int mBase = blockIdx.x * 128;
  const int nBase = blockIdx.y * 128;

  f32x4v acc[4][4];
#pragma unroll
  for (int i = 0; i < 4; ++i)
#pragma unroll
    for (int j = 0; j < 4; ++j) acc[i][j] = (f32x4v){0.f, 0.f, 0.f, 0.f};

  const int srow = w * 32 + (lane >> 3);
  const int scol = ((lane & 7) ^ (lane >> 3)) * 8;
  const u16* Ag = A + (size_t)(mBase + srow) * K1 + scol;
  const u16* Bg = B + (size_t)(nBase + srow) * K1 + scol;

  for (int k0 = 0; k0 < K1; k0 += 64) {
#pragma unroll
    for (int c = 0; c < 4; ++c) {
      __builtin_amdgcn_global_load_lds(
          (const __attribute__((address_space(1))) void*)(Ag + k0 + (size_t)c * 8 * K1),
          (__attribute__((address_space(3))) void*)(As + (w * 32 + c * 8) * 64), 16, 0, 0);
    }
#pragma unroll
    for (int c = 0; c < 4; ++c) {
      __builtin_amdgcn_global_load_lds(
          (const __attribute__((address_space(1))) void*)(Bg + k0 + (size_t)c * 8 * K1),
          (__attribute__((address_space(3))) void*)(Bs + (w * 32 + c * 8) * 64), 16, 0, 0);
    }
    __syncthreads();
#pragma unroll
    for (int kk = 0; kk < 64; kk += 32) {
      bf16x8v af[4], bfr[4];
      const int sw = lm & 7;
#pragma unroll
      for (int i = 0; i < 4; ++i) {
        int row = wm * 64 + i * 16 + lm;
        int kch = (kk >> 3) + q;
        af[i] = *(const bf16x8v*)(As + row * 64 + ((kch ^ sw) << 3));
      }
#pragma unroll
      for (int j = 0; j < 4; ++j) {
        int row = wn * 64 + j * 16 + lm;
        int kch = (kk >> 3) + q;
        bfr[j] = *(const bf16x8v*)(Bs + row * 64 + ((kch ^ sw) << 3));
      }
#pragma unroll
      for (int i = 0; i < 4; ++i)
#pragma unroll
        for (int j = 0; j < 4; ++j)
          acc[i][j] = __builtin_amdgcn_mfma_f32_16x16x32_bf16(af[i], bfr[j], acc[i][j], 0, 0, 0);
    }
    __syncthreads();
  }

  // C/D layout: col = lane&15, row = quad*4 + reg
  float bj[4];
#pragma unroll
  for (int j = 0; j < 4; ++j) bj[j] = bias[nBase + wn * 64 + j * 16 + lm];
#pragma unroll
  for (int i = 0; i < 4; ++i)
#pragma unroll
    for (int j = 0; j < 4; ++j)
#pragma unroll
      for (int r = 0; r < 4; ++r) {
        int tr = wm * 64 + i * 16 + q * 4 + r;
        int tc = wn * 64 + j * 16 + lm;
        float v = tanhf(acc[i][j][r] + bj[j]);
        int p = __builtin_amdgcn_cvt_pk_fp8_f32(v, v, 0, false);
        feat_out[(size_t)(mBase + tr) * DD + nBase + tc] = (u8)(p & 0xff);
      }
}

// ---------------- GEMM2: 128x128 MX-fp8 MFMA, 512 threads / 8 waves ----
// Round-4 spill fix: spread the accumulator tile over 8 waves.
// Wave grid 4(M) x 2(N); per-wave fragment grid 2x4 (32 rows x 64 cols).
// Per-thread live: 32 acc + 16 af + 8 bfr + addr ≈ 75 VGPRs (was ~130 -> spill).
// Same block tile / staging / MFMA economics as the 4-wave version.
__launch_bounds__(512, 2)
__global__ void gemm2_kernel(const u8* __restrict__ A, const u8* __restrict__ B,
                             const int* __restrict__ tags,
                             float* __restrict__ pmax, float* __restrict__ psum,
                             float* __restrict__ ltag) {
  __shared__ __align__(16) u8 As[128 * 128];
  __shared__ __align__(16) u8 Bs[128 * 128];
  __shared__ float rmax[2][128];
  __shared__ float rsum[2][128];
  __shared__ int   stags[128];

  const int tid  = threadIdx.x;
  const int lane = tid & 63;
  const int w    = tid >> 6;       // wave 0..7
  const int wm   = w >> 1;         // wave row 0..3 (32 rows each)
  const int wn   = w & 1;          // wave col 0..1 (64 cols each)
  const int q    = lane >> 4;
  const int lm   = lane & 15;
  const int mBase = blockIdx.x * 128;
  const int nBase = blockIdx.y * 128;

  if (tid < 128) stags[tid] = tags[mBase + tid];

  f32x4v acc[2][4];
#pragma unroll
  for (int i = 0; i < 2; ++i)
#pragma unroll
    for (int j = 0; j < 4; ++j) acc[i][j] = (f32x4v){0.f, 0.f, 0.f, 0.f};

  // staging: 8 waves x 16 rows per matrix (2 issues of 8 rows each).
  // lane i -> LDS row (i>>3), chunk (i&7) within the 8-row group; fetches
  // global chunk (i&7)^(i>>3) so LDS[r][c] = G[r][c ^ (r&7)] (16 B chunks).
  const int srow = w * 16 + (lane >> 3);
  const int scol = ((lane & 7) ^ (lane >> 3)) * 16;   // bytes
  const u8* Ag = A + (size_t)(mBase + srow) * DD + scol;
  const u8* Bg = B + (size_t)(nBase + srow) * DD + scol;

  for (int k0 = 0; k0 < DD; k0 += 128) {
#pragma unroll
    for (int c = 0; c < 2; ++c) {
      __builtin_amdgcn_global_load_lds(
          (const __attribute__((address_space(1))) void*)(Ag + k0 + (size_t)c * 8 * DD),
          (__attribute__((address_space(3))) void*)(As + (w * 16 + c * 8) * 128), 16, 0, 0);
    }
#pragma unroll
    for (int c = 0; c < 2; ++c) {
      __builtin_amdgcn_global_load_lds(
          (const __attribute__((address_space(1))) void*)(Bg + k0 + (size_t)c * 8 * DD),
          (__attribute__((address_space(3))) void*)(Bs + (w * 16 + c * 8) * 128), 16, 0, 0);
    }
    __syncthreads();

    // lane (m=lm, kgroup=q) needs global chunks 2q, 2q+1 of its row
    const int sw = lm & 7;
    const int c0 = ((2 * q) ^ sw) * 16;
    const int c1 = ((2 * q + 1) ^ sw) * 16;
    i32x8v af[2];
#pragma unroll
    for (int i = 0; i < 2; ++i) {
      int row = wm * 32 + i * 16 + lm;
      i32x4v lo = *(const i32x4v*)(As + row * 128 + c0);
      i32x4v hi = *(const i32x4v*)(As + row * 128 + c1);
      af[i] = __builtin_shufflevector(lo, hi, 0, 1, 2, 3, 4, 5, 6, 7);
    }
#pragma unroll
    for (int j = 0; j < 4; ++j) {
      int row = wn * 64 + j * 16 + lm;
      i32x4v lo = *(const i32x4v*)(Bs + row * 128 + c0);
      i32x4v hi = *(const i32x4v*)(Bs + row * 128 + c1);
      i32x8v bfr = __builtin_shufflevector(lo, hi, 0, 1, 2, 3, 4, 5, 6, 7);
#pragma unroll
      for (int i = 0; i < 2; ++i)
        acc[i][j] = __builtin_amdgcn_mfma_scale_f32_16x16x128_f8f6f4(
            af[i], bfr, acc[i][j], 0, 0, 0, SCALE1, 0, SCALE1);
    }
    __syncthreads();
  }

  // C/D layout: col = lane&15, row = quad*4 + reg
  // phase 1: per-row max over this wave's 64 cols -> LDS
#pragma unroll
  for (int i = 0; i < 2; ++i)
#pragma unroll
    for (int r = 0; r < 4; ++r) {
      float m = fmaxf(fmaxf(acc[i][0][r], acc[i][1][r]),
                      fmaxf(acc[i][2][r], acc[i][3][r]));
#pragma unroll
      for (int off = 1; off < 16; off <<= 1) m = fmaxf(m, __shfl_xor(m, off, 64));
      if (lm == 0) rmax[wn][wm * 32 + i * 16 + q * 4 + r] = m;
    }
  __syncthreads();
  // phase 2: sumexp against the full 128-col row max
#pragma unroll
  for (int i = 0; i < 2; ++i)
#pragma unroll
    for (int r = 0; r < 4; ++r) {
      int tr = wm * 32 + i * 16 + q * 4 + r;
      float M = fmaxf(rmax[0][tr], rmax[1][tr]);
      float s = __expf(acc[i][0][r] - M) + __expf(acc[i][1][r] - M) +
                __expf(acc[i][2][r] - M) + __expf(acc[i][3][r] - M);
#pragma unroll
      for (int off = 1; off < 16; off <<= 1) s += __shfl_xor(s, off, 64);
      if (lm == 0) rsum[wn][tr] = s;
    }
  __syncthreads();
  if (tid < 128) {
    float M = fmaxf(rmax[0][tid], rmax[1][tid]);
    float S = rsum[0][tid] + rsum[1][tid];
    pmax[(size_t)blockIdx.y * LSPANS + mBase + tid] = M;
    psum[(size_t)blockIdx.y * LSPANS + mBase + tid] = S;
  }
  // tag logit capture (exactly one matching column per row globally)
#pragma unroll
  for (int i = 0; i < 2; ++i)
#pragma unroll
    for (int r = 0; r < 4; ++r) {
      int tr = wm * 32 + i * 16 + q * 4 + r;
      int tg = stags[tr];
#pragma unroll
      for (int j = 0; j < 4; ++j) {
        int gc = nBase + wn * 64 + j * 16 + lm;
        if (tg == gc) ltag[mBase + tr] = acc[i][j][r];
      }
    }
}

// ---------------- merge partials, weighted-mean NLL ----------------
__global__ void finalize_kernel(const float* __restrict__ pmax, const float* __restrict__ psum,
                                const float* __restrict__ ltag, const int* __restrict__ tags,
                                const float* __restrict__ dprob, float* __restrict__ out) {
  int l = blockIdx.x * blockDim.x + threadIdx.x;
  const float* pm = pmax + l;
  const float* ps = psum + l;
  float M = -1e30f;
  for (int t = 0; t < NT2; ++t) M = fmaxf(M, pm[(size_t)t * LSPANS]);
  float S = 0.f;
  for (int t = 0; t < NT2; ++t) S += ps[(size_t)t * LSPANS] * __expf(pm[(size_t)t * LSPANS] - M);
  float nll = M + logf(S) - ltag[l];
  float wgt = 1.0f - dprob[tags[l]];
  float val = nll * wgt * (1.0f / (4096.0f + 1e-5f));
  __shared__ float red[4];
#pragma unroll
  for (int off = 32; off; off >>= 1) val += __shfl_down(val, off, 64);
  if ((threadIdx.x & 63) == 0) red[threadIdx.x >> 6] = val;
  __syncthreads();
  if (threadIdx.x == 0) atomicAdd(out, red[0] + red[1] + red[2] + red[3]);
}

extern "C" void kernel_launch(void* const* d_in, const int* in_sizes, int n_in,
                              void* d_out, int out_size, void* d_ws, size_t ws_size,
                              hipStream_t stream) {
  const float* hidden = (const float*)d_in[0];
  const float* W1     = (const float*)d_in[1];
  const float* b1     = (const float*)d_in[2];
  const float* Wout   = (const float*)d_in[3];
  const float* dprob  = (const float*)d_in[4];
  const int*   bid    = (const int*)d_in[5];
  const int*   sb     = (const int*)d_in[6];
  const int*   se     = (const int*)d_in[7];
  const int*   tags   = (const int*)d_in[8];
  float* out = (float*)d_out;

  char* ws = (char*)d_ws;
  u16* A1     = (u16*)ws;                ws += (size_t)LSPANS * K1 * 2;      // 16.78 MB
  u16* W1b    = (u16*)ws;                ws += (size_t)DD * K1 * 2;          //  4.19 MB
  u8*  Wout8  = (u8*)ws;                 ws += (size_t)VV * DD;              // 32.77 MB
  u8*  feat8  = (u8*)ws;                 ws += (size_t)LSPANS * DD;          //  4.19 MB
  float* pmax = (float*)ws;              ws += (size_t)NT2 * LSPANS * 4;     //  4.10 MB
  float* psum = (float*)ws;              ws += (size_t)NT2 * LSPANS * 4;     //  4.10 MB
  float* ltag = (float*)ws;              ws += (size_t)LSPANS * 4;

  hipMemsetAsync(d_out, 0, sizeof(float), stream);

  // conversions
  {
    int n4 = DD * K1 / 4;
    cvt_kernel<<<(n4 + 255) / 256, 256, 0, stream>>>(W1, W1b, n4);
  }
  {
    int n4 = VV * DD / 4;
    cvt_fp8_kernel<<<(n4 + 255) / 256, 256, 0, stream>>>(Wout, (int*)Wout8, n4);
  }
  // gather span endpoint embeddings
  gather_kernel<<<LSPANS, 256, 0, stream>>>(hidden, bid, sb, se, A1);

  // GEMM1: feat8 = fp8(tanh(A1 @ W1^T + b1))   [4096 x 1024]
  gemm1_kernel<<<dim3(LSPANS / 128, DD / 128), 256, 0, stream>>>(A1, W1b, b1, feat8);

  // GEMM2: MX-fp8 logits tiles + fused softmax partials   [4096 x 32000]
  gemm2_kernel<<<dim3(LSPANS / 128, NT2), 512, 0, stream>>>(feat8, Wout8, tags, pmax, psum, ltag);

  // merge + weighted mean
  finalize_kernel<<<LSPANS / 256, 256, 0, stream>>>(pmax, psum, ltag, tags, dprob, out);
}